// Round 4
// baseline (3155.491 us; speedup 1.0000x reference)
//
#include <hip/hip_runtime.h>
#include <cstdint>

// Problem dims
#define V_    32000
#define E_    512
#define H_    1024
#define N_    32
#define T_    256
#define TS    255          // steps = T-1
#define NWG_B 64           // phase B workgroups (1 wave each)
#define CB_   250          // phase C col blocks (250*128 = 32000)
#define RB_   64           // phase C row blocks (64*128 = 8192; rows 8160..8191 pad)
#define MROW  8192
#define GI_CB 24           // Gi GEMM col blocks (24*128 = 3072)

typedef _Float16 f16;
typedef _Float16 half8 __attribute__((ext_vector_type(8)));
typedef float floatx4 __attribute__((ext_vector_type(4)));
typedef unsigned long long u64;

// ---------------- prep kernels ----------------

__global__ void prep_emit16(const float* __restrict__ emit_w, f16* __restrict__ out) {
  const int64_t nchunk = (int64_t)V_ * H_ / 8;
  int64_t i = (int64_t)blockIdx.x * blockDim.x + threadIdx.x;
  for (; i < nchunk; i += (int64_t)gridDim.x * blockDim.x) {
    const float4* src = (const float4*)(emit_w + i * 8);
    float4 a = src[0], b = src[1];
    half8 h;
    h[0] = (f16)a.x; h[1] = (f16)a.y; h[2] = (f16)a.z; h[3] = (f16)a.w;
    h[4] = (f16)b.x; h[5] = (f16)b.y; h[6] = (f16)b.z; h[7] = (f16)b.w;
    *(half8*)(out + i * 8) = h;
  }
}

// w_hh -> MFMA B-fragment order: whh[(jt*32+kt)*64+lane][8] =
//   w_hh[col = jt*16 + (lane&15)][k = kt*32 + (lane>>4)*8 + i], jt in [0,192), kt in [0,32)
__global__ void prep_whh(const float* __restrict__ w_hh, f16* __restrict__ whh) {
  int idx = blockIdx.x * blockDim.x + threadIdx.x;   // 192*32*64 = 393216
  if (idx >= 192 * 32 * 64) return;
  int lane = idx & 63;
  int kt   = (idx >> 6) & 31;
  int jt   = (idx >> 6) >> 5;
  int col  = jt * 16 + (lane & 15);
  int k0   = kt * 32 + (lane >> 4) * 8;
  const float* src = w_hh + (int64_t)col * H_ + k0;
  half8 h;
#pragma unroll
  for (int i = 0; i < 8; ++i) h[i] = (f16)src[i];
  *(half8*)(whh + (int64_t)idx * 8) = h;
}

// w_ih f32[3072][512] -> f16 row-major (B operand of Gi GEMM)
__global__ void prep_wih16(const float* __restrict__ w_ih, f16* __restrict__ out) {
  int idx = blockIdx.x * blockDim.x + threadIdx.x;   // 3072*512/8 = 196608
  if (idx >= 3072 * 512 / 8) return;
  const float4* src = (const float4*)(w_ih + (int64_t)idx * 8);
  float4 a = src[0], b = src[1];
  half8 h;
  h[0] = (f16)a.x; h[1] = (f16)a.y; h[2] = (f16)a.z; h[3] = (f16)a.w;
  h[4] = (f16)b.x; h[5] = (f16)b.y; h[6] = (f16)b.z; h[7] = (f16)b.w;
  *(half8*)(out + (int64_t)idx * 8) = h;
}

// Xemb[t*32+n][0:512] = (f16) embed_w[words[n][t]][:]
__global__ void prep_xemb(const int* __restrict__ words, const float* __restrict__ embed_w,
                          f16* __restrict__ xemb) {
  int idx = blockIdx.x * blockDim.x + threadIdx.x;   // 255*32*64 = 522240
  if (idx >= TS * N_ * (E_ / 8)) return;
  int u = idx & 63;
  int n = (idx >> 6) & 31;
  int t = idx >> 11;
  int word = words[n * T_ + t];
  const float* src = embed_w + (int64_t)word * E_ + u * 8;
  half8 h;
#pragma unroll
  for (int i = 0; i < 8; ++i) h[i] = (f16)src[i];
  *(half8*)(xemb + (int64_t)(t * N_ + n) * E_ + u * 8) = h;
}

// init h0 (f16) and zero flag slots
__global__ void prep_init(const float* __restrict__ h0, f16* __restrict__ xh,
                          unsigned* __restrict__ slots) {
  int idx = blockIdx.x * blockDim.x + threadIdx.x;
  if (idx < N_ * H_) xh[idx] = (f16)h0[idx];
  if (idx < 1024) slots[idx] = 0;
}

// ---------------- Gi GEMM: Xemb[8192x512] @ wih16^T -> Gi2[t][3072][32] f16 ----------------

#define LDK 72   // +8 f16 pad per 64-f16 row slice: breaks ds_read_b128 bank conflicts

__launch_bounds__(256, 2)
__global__ void gi_gemm(const f16* __restrict__ xemb, const f16* __restrict__ wih16,
                        f16* __restrict__ gi2) {
  const int cb = blockIdx.x % GI_CB;
  const int rb = blockIdx.x / GI_CB;
  const int tid = threadIdx.x;
  const int w = tid >> 6, lane = tid & 63;
  const int wm = w & 1, wn = w >> 1;
  const int l15 = lane & 15, l4 = lane >> 4;

  __shared__ f16 lA[128 * LDK];
  __shared__ f16 lB[128 * LDK];

  floatx4 acc[4][4];
#pragma unroll
  for (int mt = 0; mt < 4; ++mt)
#pragma unroll
    for (int nt = 0; nt < 4; ++nt) { acc[mt][nt][0] = 0.f; acc[mt][nt][1] = 0.f; acc[mt][nt][2] = 0.f; acc[mt][nt][3] = 0.f; }

  const f16* gA = xemb + (int64_t)rb * 128 * E_;
  const f16* gB = wih16 + (int64_t)cb * 128 * E_;

  for (int kb = 0; kb < 8; ++kb) {
    __syncthreads();
#pragma unroll
    for (int i = 0; i < 4; ++i) {
      int idx = i * 256 + tid;
      int row = idx >> 3, u = idx & 7;
      int64_t goff = (int64_t)row * E_ + kb * 64 + u * 8;
      *(half8*)(lA + row * LDK + u * 8) = *(const half8*)(gA + goff);
      *(half8*)(lB + row * LDK + u * 8) = *(const half8*)(gB + goff);
    }
    __syncthreads();
#pragma unroll
    for (int ks = 0; ks < 2; ++ks) {
      half8 af[4], bf[4];
#pragma unroll
      for (int mt = 0; mt < 4; ++mt)
        af[mt] = *(const half8*)(lA + (wm * 64 + mt * 16 + l15) * LDK + ks * 32 + l4 * 8);
#pragma unroll
      for (int nt = 0; nt < 4; ++nt)
        bf[nt] = *(const half8*)(lB + (wn * 64 + nt * 16 + l15) * LDK + ks * 32 + l4 * 8);
#pragma unroll
      for (int mt = 0; mt < 4; ++mt)
#pragma unroll
        for (int nt = 0; nt < 4; ++nt)
          acc[mt][nt] = __builtin_amdgcn_mfma_f32_16x16x32_f16(af[mt], bf[nt], acc[mt][nt], 0, 0, 0);
    }
  }

  // epilogue: Gi2[((t*3072)+col)*32 + n], col = cb*128 + wn*64 + nt*16 + l15
#pragma unroll
  for (int mt = 0; mt < 4; ++mt) {
#pragma unroll
    for (int r = 0; r < 4; ++r) {
      int g = rb * 128 + wm * 64 + mt * 16 + l4 * 4 + r;
      if (g < TS * N_) {
        int tt = g >> 5, n = g & 31;
        f16* gb = gi2 + ((int64_t)tt * 3072 + cb * 128 + wn * 64) * 32 + n;
#pragma unroll
        for (int nt = 0; nt < 4; ++nt)
          gb[(nt * 16 + l15) * 32] = (f16)acc[mt][nt][r];
      }
    }
  }
}

// ---------------- phase B: persistent GRU recurrence, 1 wave/wg, zero barriers ----------------
// wg b (one 64-lane wave) owns h-cols [b*16, b*16+16), computes full K=1024 itself:
// 192 MFMAs/step (3 gates x 32 ktiles x 2 mtiles), weights streamed from LDS (96KB).
// h history is WRITE-ONCE: step t's h goes to hall[t] (agent-scope packed 4B stores);
// consumers read hall[t-1] with PLAIN 16B loads (each line read once per consumer ->
// no stale-L2 risk; fresh-line property). Sync: 8 stores -> s_waitcnt(0) -> 1 flag
// per wg; consumer lane l polls flag[l] (64 producer wgs, dedicated 64B lines).

__device__ inline unsigned aload32(const void* p) {
  return __hip_atomic_load((const unsigned*)p, __ATOMIC_RELAXED, __HIP_MEMORY_SCOPE_AGENT);
}

__launch_bounds__(64, 1)
__global__ void phaseB(const f16* __restrict__ whh, const f16* __restrict__ gi2,
                       const f16* __restrict__ h0f16, const float* __restrict__ b_ih,
                       const float* __restrict__ b_hh, f16* __restrict__ hall,
                       float* __restrict__ out, unsigned* __restrict__ slots) {
  const int b = blockIdx.x;
  const int lane = threadIdx.x;        // 0..63
  const int l15 = lane & 15, l4 = lane >> 4;
  const int j = b * 16 + l15;          // this lane's output col

  __shared__ half8 lw[3 * 32 * 64];    // 96 KB: [gate][ktile][lane] B-fragments

  // preload this wg's weight fragments (once)
  for (int i = 0; i < 96; ++i) {
    int e = i * 64 + lane;             // 0..6143
    int g  = e >> 11;
    int kt = (e >> 6) & 31;
    int le = e & 63;
    lw[e] = *(const half8*)(whh + (((int64_t)(g * 64 + b) * 32 + kt) * 64 + le) * 8);
  }
  __syncthreads();   // lgkm drain (single wave)

  const float biasr = b_ih[j] + b_hh[j];
  const float biasz = b_ih[H_ + j] + b_hh[H_ + j];
  const float bihn  = b_ih[2 * H_ + j];
  const float bhhn  = b_hh[2 * H_ + j];

  // carried h (f16-roundtripped): 8 values, n = m*16 + l4*4 + r
  float hold[2][4];
#pragma unroll
  for (int m = 0; m < 2; ++m)
#pragma unroll
    for (int r = 0; r < 4; ++r)
      hold[m][r] = (float)h0f16[(m * 16 + l4 * 4 + r) * H_ + j];

  const unsigned* pollp = slots + lane * 16;   // producer wg `lane`'s flag
  unsigned* ownflag = slots + b * 16;

  for (int t = 0; t < TS; ++t) {
    // gate inputs (written before phaseB; plain cached loads), issued early
    const f16* gp = gi2 + ((int64_t)t * 3072 + j) * 32 + l4 * 4;
    u64 gvu[3][2];
#pragma unroll
    for (int g = 0; g < 3; ++g)
#pragma unroll
      for (int m = 0; m < 2; ++m)
        gvu[g][m] = *(const u64*)(gp + g * (H_ * 32) + m * 16);

    // wait until all 64 producer wgs finished step t-1 (t=0: flags 0, passes)
    while (aload32(pollp) < (unsigned)t) __builtin_amdgcn_s_sleep(1);

    const f16* hp = (t == 0) ? h0f16 : (hall + (int64_t)(t - 1) * N_ * H_);

    floatx4 acc[3][2];
#pragma unroll
    for (int g = 0; g < 3; ++g)
#pragma unroll
      for (int m = 0; m < 2; ++m) { acc[g][m][0] = 0.f; acc[g][m][1] = 0.f; acc[g][m][2] = 0.f; acc[g][m][3] = 0.f; }

    // full-K MFMA stream: plain 16B A loads (write-once lines), LDS B frags
#pragma unroll
    for (int kt = 0; kt < 32; ++kt) {
      const f16* base = hp + kt * 32 + l4 * 8;
      half8 a0 = *(const half8*)(base + (int64_t)l15 * H_);
      half8 a1 = *(const half8*)(base + (int64_t)(l15 + 16) * H_);
#pragma unroll
      for (int g = 0; g < 3; ++g) {
        half8 bf = lw[(g * 32 + kt) * 64 + lane];
        acc[g][0] = __builtin_amdgcn_mfma_f32_16x16x32_f16(a0, bf, acc[g][0], 0, 0, 0);
        acc[g][1] = __builtin_amdgcn_mfma_f32_16x16x32_f16(a1, bf, acc[g][1], 0, 0, 0);
      }
    }

    // gate nonlinearity; C/D: col=l15 (j), row = l4*4 + r (+16 for m=1)
    unsigned pk[2][4];
    float hn[2][4];
#pragma unroll
    for (int m = 0; m < 2; ++m) {
#pragma unroll
      for (int r = 0; r < 4; ++r) {
        float gvr = (float)__builtin_bit_cast(f16, (unsigned short)(gvu[0][m] >> (16 * r)));
        float gvz = (float)__builtin_bit_cast(f16, (unsigned short)(gvu[1][m] >> (16 * r)));
        float gvn = (float)__builtin_bit_cast(f16, (unsigned short)(gvu[2][m] >> (16 * r)));
        float gr = biasr + gvr + acc[0][m][r];
        float gz = biasz + gvz + acc[1][m][r];
        float rg = 1.f / (1.f + __expf(-gr));
        float zg = 1.f / (1.f + __expf(-gz));
        float nn = tanhf(bihn + gvn + rg * (bhhn + acc[2][m][r]));
        float hnew = (1.f - zg) * nn + zg * hold[m][r];
        unsigned short hb = __builtin_bit_cast(unsigned short, (f16)hnew);
        unsigned other = (unsigned)__shfl_xor((int)(unsigned)hb, 1, 64) & 0xffffu;
        pk[m][r] = (unsigned)hb | (other << 16);
        hn[m][r] = hnew;
        hold[m][r] = (float)(f16)hnew;
      }
    }

    // publish h_t to hall[t] (agent-scope; even-j lanes store packed pairs)
    f16* hw = hall + (int64_t)t * N_ * H_;
    if (!(l15 & 1)) {
#pragma unroll
      for (int m = 0; m < 2; ++m)
#pragma unroll
        for (int r = 0; r < 4; ++r) {
          int n = m * 16 + l4 * 4 + r;
          __hip_atomic_store((unsigned*)(hw + n * H_ + j), pk[m][r],
                             __ATOMIC_RELAXED, __HIP_MEMORY_SCOPE_AGENT);
        }
    }
    if (t < TS - 1) {
      __builtin_amdgcn_s_waitcnt(0);       // all h stores acked at coherence point
      if (lane == 0)
        __hip_atomic_store(ownflag, (unsigned)(t + 1),
                           __ATOMIC_RELAXED, __HIP_MEMORY_SCOPE_AGENT);
    } else {
#pragma unroll
      for (int m = 0; m < 2; ++m)
#pragma unroll
        for (int r = 0; r < 4; ++r) {
          int n = m * 16 + l4 * 4 + r;
          out[32 + n * H_ + j] = hn[m][r];
        }
    }
  }
}

// ---------------- phase C: logits GEMM + per-row sum(exp) partials ----------------
// m97 structure: global_load_lds(16B) direct staging, linear LDS [128][64] f16,
// both-sides XOR swizzle (src chunk c^row&7, read col ^ (row&7)<<3) for
// conflict-free ds_read_b128. XCD-chunked work mapping: each XCD gets 2000
// consecutive works in cb-major order -> B-tile L2-resident per cb-group.

__device__ inline void gload_lds16(const f16* g, f16* l) {
  __builtin_amdgcn_global_load_lds((const __attribute__((address_space(1))) void*)g,
                                   (__attribute__((address_space(3))) void*)l, 16, 0, 0);
}

__launch_bounds__(256, 2)
__global__ void phaseC(const f16* __restrict__ hall, const f16* __restrict__ emit16,
                       const float* __restrict__ emit_b, float* __restrict__ spart) {
  // bijective XCD-chunk swizzle: 16000 wgs, 2000 per XCD, cb-major work order
  const int wgid = (blockIdx.x & 7) * 2000 + (blockIdx.x >> 3);
  const int cb = wgid >> 6;       // 0..249  (B col-block; reused by 64 rbs on same XCD)
  const int rb = wgid & 63;       // 0..63
  const int tid = threadIdx.x;
  const int w = tid >> 6, lane = tid & 63;
  const int wm = w & 1, wn = w >> 1;
  const int l15 = lane & 15, l4 = lane >> 4;

  __shared__ f16 lA[128 * 64];
  __shared__ f16 lB[128 * 64];
  __shared__ float rs[2][128];

  floatx4 acc[4][4];
#pragma unroll
  for (int mt = 0; mt < 4; ++mt)
#pragma unroll
    for (int nt = 0; nt < 4; ++nt) { acc[mt][nt][0] = 0.f; acc[mt][nt][1] = 0.f; acc[mt][nt][2] = 0.f; acc[mt][nt][3] = 0.f; }

  const f16* gA = hall + (int64_t)rb * 128 * H_;
  const f16* gB = emit16 + (int64_t)cb * 128 * H_;

  const int lrow8 = lane >> 3;                 // dest row within 8-row block = row&7
  const int sc = (lane & 7) ^ lrow8;           // pre-swizzled source chunk
  const int rdx = (l15 & 7) << 3;              // read-side XOR (elements) for A/B frags

  for (int kb = 0; kb < 16; ++kb) {
    __syncthreads();
#pragma unroll
    for (int i = 0; i < 4; ++i) {
      const int r0 = w * 32 + i * 8;           // wave-uniform row-block base
      const int64_t goff = (int64_t)(r0 + lrow8) * H_ + kb * 64 + sc * 8;
      gload_lds16(gA + goff, lA + r0 * 64);
      gload_lds16(gB + goff, lB + r0 * 64);
    }
    __syncthreads();                           // drains vmcnt(0): stage visible
#pragma unroll
    for (int ks = 0; ks < 2; ++ks) {
      half8 af[4], bf[4];
      const int col = (ks * 32 + l4 * 8) ^ rdx;
#pragma unroll
      for (int mt = 0; mt < 4; ++mt)
        af[mt] = *(const half8*)(lA + (wm * 64 + mt * 16 + l15) * 64 + col);
#pragma unroll
      for (int nt = 0; nt < 4; ++nt)
        bf[nt] = *(const half8*)(lB + (wn * 64 + nt * 16 + l15) * 64 + col);
#pragma unroll
      for (int mt = 0; mt < 4; ++mt)
#pragma unroll
        for (int nt = 0; nt < 4; ++nt)
          acc[mt][nt] = __builtin_amdgcn_mfma_f32_16x16x32_f16(af[mt], bf[nt], acc[mt][nt], 0, 0, 0);
    }
  }

  // |logits| bounded (|h|<1, |emit_w|<~0.032) -> no max-subtraction needed
  float eb[4];
#pragma unroll
  for (int nt = 0; nt < 4; ++nt) eb[nt] = emit_b[cb * 128 + wn * 64 + nt * 16 + l15];

#pragma unroll
  for (int mt = 0; mt < 4; ++mt) {
#pragma unroll
    for (int r = 0; r < 4; ++r) {
      float s = 0.f;
#pragma unroll
      for (int nt = 0; nt < 4; ++nt) s += __expf(acc[mt][nt][r] + eb[nt]);
#pragma unroll
      for (int off = 1; off < 16; off <<= 1) s += __shfl_xor(s, off, 64);
      if (l15 == 0) rs[wn][wm * 64 + mt * 16 + l4 * 4 + r] = s;
    }
  }
  __syncthreads();
  if (tid < 128)
    spart[(int64_t)cb * MROW + rb * 128 + tid] = rs[0][tid] + rs[1][tid];
}

// ---------------- target logits + final reductions ----------------

__global__ void target_dots(const f16* __restrict__ hall, const f16* __restrict__ emit16,
                            const int* __restrict__ words, const float* __restrict__ emit_b,
                            float* __restrict__ tlog) {
  int r = blockIdx.x * 4 + (threadIdx.x >> 6);
  if (r >= TS * N_) return;
  int lane = threadIdx.x & 63;
  int t = r >> 5, n = r & 31;
  int tgt = words[n * T_ + t + 1];
  const f16* ha = hall + (int64_t)r * H_;
  const f16* ebp = emit16 + (int64_t)tgt * H_;
  float s = 0.f;
#pragma unroll
  for (int c = 0; c < 2; ++c) {
    int k = c * 512 + lane * 8;
    half8 a = *(const half8*)(ha + k);
    half8 b = *(const half8*)(ebp + k);
#pragma unroll
    for (int i = 0; i < 8; ++i) s += (float)a[i] * (float)b[i];
  }
#pragma unroll
  for (int off = 1; off < 64; off <<= 1) s += __shfl_xor(s, off, 64);
  if (lane == 0) tlog[r] = s + emit_b[tgt];
}

__global__ void reduce_lse(const float* __restrict__ spart, const float* __restrict__ tlog,
                           float* __restrict__ lval) {
  int r = blockIdx.x * blockDim.x + threadIdx.x;
  if (r >= TS * N_) return;
  float s = 0.f;
  for (int cb = 0; cb < CB_; ++cb) s += spart[(int64_t)cb * MROW + r];
  lval[r] = tlog[r] - logf(s);
}

__global__ void finalize(const float* __restrict__ lval, float* __restrict__ out) {
  __shared__ float ps[8][32];
  int n = threadIdx.x & 31, sl = threadIdx.x >> 5;
  float s = 0.f;
  for (int i = 0; i < 32; ++i) {
    int t = sl * 32 + i;
    if (t < TS) s += lval[t * N_ + n];
  }
  ps[sl][n] = s;
  __syncthreads();
  if (threadIdx.x < 32) {
    float tot = 0.f;
#pragma unroll
    for (int k = 0; k < 8; ++k) tot += ps[k][threadIdx.x];
    out[threadIdx.x] = tot;
  }
}

// ---------------- launch ----------------

extern "C" void kernel_launch(void* const* d_in, const int* in_sizes, int n_in,
                              void* d_out, int out_size, void* d_ws, size_t ws_size,
                              hipStream_t stream) {
  (void)in_sizes; (void)n_in; (void)out_size; (void)ws_size;
  const int*   words   = (const int*)d_in[0];
  const float* h0      = (const float*)d_in[1];
  const float* embed_w = (const float*)d_in[2];
  const float* w_ih    = (const float*)d_in[3];
  const float* w_hh    = (const float*)d_in[4];
  const float* b_ih    = (const float*)d_in[5];
  const float* b_hh    = (const float*)d_in[6];
  const float* emit_w  = (const float*)d_in[7];
  const float* emit_b  = (const float*)d_in[8];
  float* out = (float*)d_out;

  char* ws = (char*)d_ws;
  // ws layout (bytes), total ~100.4 MB. Aliases:
  //  - big region: Gi2 (f16, 50.1 MB, dead after phaseB) then emit16 (65.5 MB, built after phaseB)
  //  - spart (8.19 MB, phaseC) aliases wih16 (dead after gi_gemm)
  f16*      big    = (f16*)(ws + 0);                // 65,536,000
  f16*      gi2    = big;
  f16*      emit16 = big;
  f16*      whh    = (f16*)(ws + 65536000);         //  6,291,456
  f16*      wih16  = (f16*)(ws + 71827456);         //  3,145,728
  float*    spart  = (float*)(ws + 71827456);       //  8,192,000 (alias)
  f16*      xemb   = (f16*)(ws + 74973184);         //  8,388,608 (8192 rows x 512)
  f16*      xh     = (f16*)(ws + 83361792);         //    131,072 (h0 as f16)
  f16*      hall   = (f16*)(ws + 83492864);         // 16,777,216 (write-once h history)
  float*    tlog   = (float*)(ws + 100270080);      //     32,640
  float*    lval   = (float*)(ws + 100302720);      //     32,640
  unsigned* slots  = (unsigned*)(ws + 100335360);   //      4,096 (64 wg-flags x 64B)

  hipLaunchKernelGGL(prep_whh, dim3(1536), dim3(256), 0, stream, w_hh, whh);
  hipLaunchKernelGGL(prep_wih16, dim3(768), dim3(256), 0, stream, w_ih, wih16);
  hipLaunchKernelGGL(prep_xemb, dim3(2040), dim3(256), 0, stream, words, embed_w, xemb);
  hipLaunchKernelGGL(prep_init, dim3(128), dim3(256), 0, stream, h0, xh, slots);
  hipLaunchKernelGGL(gi_gemm, dim3(RB_ * GI_CB), dim3(256), 0, stream, xemb, wih16, gi2);
  hipLaunchKernelGGL(phaseB, dim3(NWG_B), dim3(64), 0, stream, whh, gi2, xh, b_ih, b_hh, hall, out, slots);
  hipLaunchKernelGGL(prep_emit16, dim3(4096), dim3(256), 0, stream, emit_w, emit16);
  hipLaunchKernelGGL(phaseC, dim3(RB_ * CB_), dim3(256), 0, stream, hall, emit16, emit_b, spart);
  hipLaunchKernelGGL(target_dots, dim3((TS * N_ + 3) / 4), dim3(256), 0, stream, hall, emit16, words, emit_b, tlog);
  hipLaunchKernelGGL(reduce_lse, dim3((TS * N_ + 255) / 256), dim3(256), 0, stream, spart, tlog, lval);
  hipLaunchKernelGGL(finalize, dim3(1), dim3(256), 0, stream, lval, out);
}

// Round 5
// 2868.431 us; speedup vs baseline: 1.1001x; 1.1001x over previous
//
#include <hip/hip_runtime.h>
#include <cstdint>

// Problem dims
#define V_    32000
#define E_    512
#define H_    1024
#define N_    32
#define T_    256
#define TS    255          // steps = T-1
#define NWG_B 64           // phase B participating workgroups
#define CAND_B 1024        // phase B candidate wgs launched (claim-filtered)
#define CB_   250          // phase C col blocks (250*128 = 32000)
#define RB_   64           // phase C row blocks (64*128 = 8192; rows 8160..8191 pad)
#define MROW  8192
#define GI_CB 24           // Gi GEMM col blocks (24*128 = 3072)

typedef _Float16 f16;
typedef _Float16 half8 __attribute__((ext_vector_type(8)));
typedef float floatx4 __attribute__((ext_vector_type(4)));
typedef unsigned long long u64;

// ---------------- prep kernels ----------------

__global__ void prep_emit16(const float* __restrict__ emit_w, f16* __restrict__ out) {
  const int64_t nchunk = (int64_t)V_ * H_ / 8;
  int64_t i = (int64_t)blockIdx.x * blockDim.x + threadIdx.x;
  for (; i < nchunk; i += (int64_t)gridDim.x * blockDim.x) {
    const float4* src = (const float4*)(emit_w + i * 8);
    float4 a = src[0], b = src[1];
    half8 h;
    h[0] = (f16)a.x; h[1] = (f16)a.y; h[2] = (f16)a.z; h[3] = (f16)a.w;
    h[4] = (f16)b.x; h[5] = (f16)b.y; h[6] = (f16)b.z; h[7] = (f16)b.w;
    *(half8*)(out + i * 8) = h;
  }
}

// w_hh -> MFMA B-fragment order: whh[(jt*32+kt)*64+lane][8] =
//   w_hh[col = jt*16 + (lane&15)][k = kt*32 + (lane>>4)*8 + i], jt in [0,192), kt in [0,32)
__global__ void prep_whh(const float* __restrict__ w_hh, f16* __restrict__ whh) {
  int idx = blockIdx.x * blockDim.x + threadIdx.x;   // 192*32*64 = 393216
  if (idx >= 192 * 32 * 64) return;
  int lane = idx & 63;
  int kt   = (idx >> 6) & 31;
  int jt   = (idx >> 6) >> 5;
  int col  = jt * 16 + (lane & 15);
  int k0   = kt * 32 + (lane >> 4) * 8;
  const float* src = w_hh + (int64_t)col * H_ + k0;
  half8 h;
#pragma unroll
  for (int i = 0; i < 8; ++i) h[i] = (f16)src[i];
  *(half8*)(whh + (int64_t)idx * 8) = h;
}

// w_ih f32[3072][512] -> f16 row-major (B operand of Gi GEMM)
__global__ void prep_wih16(const float* __restrict__ w_ih, f16* __restrict__ out) {
  int idx = blockIdx.x * blockDim.x + threadIdx.x;   // 3072*512/8 = 196608
  if (idx >= 3072 * 512 / 8) return;
  const float4* src = (const float4*)(w_ih + (int64_t)idx * 8);
  float4 a = src[0], b = src[1];
  half8 h;
  h[0] = (f16)a.x; h[1] = (f16)a.y; h[2] = (f16)a.z; h[3] = (f16)a.w;
  h[4] = (f16)b.x; h[5] = (f16)b.y; h[6] = (f16)b.z; h[7] = (f16)b.w;
  *(half8*)(out + (int64_t)idx * 8) = h;
}

// Xemb[t*32+n][0:512] = (f16) embed_w[words[n][t]][:]
__global__ void prep_xemb(const int* __restrict__ words, const float* __restrict__ embed_w,
                          f16* __restrict__ xemb) {
  int idx = blockIdx.x * blockDim.x + threadIdx.x;   // 255*32*64 = 522240
  if (idx >= TS * N_ * (E_ / 8)) return;
  int u = idx & 63;
  int n = (idx >> 6) & 31;
  int t = idx >> 11;
  int word = words[n * T_ + t];
  const float* src = embed_w + (int64_t)word * E_ + u * 8;
  half8 h;
#pragma unroll
  for (int i = 0; i < 8; ++i) h[i] = (f16)src[i];
  *(half8*)(xemb + (int64_t)(t * N_ + n) * E_ + u * 8) = h;
}

// init h0 (f16); zero flags + claim counters
__global__ void prep_init(const float* __restrict__ h0, f16* __restrict__ xh,
                          unsigned* __restrict__ slots) {
  int idx = blockIdx.x * blockDim.x + threadIdx.x;
  if (idx < N_ * H_) xh[idx] = (f16)h0[idx];
  if (idx < 2048) slots[idx] = 0;   // 64 flags x 64B + ticket/target/slotcnt
}

// ---------------- Gi GEMM: Xemb[8192x512] @ wih16^T -> Gi2[t][3072][32] f16 ----------------

#define LDK 72   // +8 f16 pad per 64-f16 row slice: breaks ds_read_b128 bank conflicts

__launch_bounds__(256, 2)
__global__ void gi_gemm(const f16* __restrict__ xemb, const f16* __restrict__ wih16,
                        f16* __restrict__ gi2) {
  const int cb = blockIdx.x % GI_CB;
  const int rb = blockIdx.x / GI_CB;
  const int tid = threadIdx.x;
  const int w = tid >> 6, lane = tid & 63;
  const int wm = w & 1, wn = w >> 1;
  const int l15 = lane & 15, l4 = lane >> 4;

  __shared__ f16 lA[128 * LDK];
  __shared__ f16 lB[128 * LDK];

  floatx4 acc[4][4];
#pragma unroll
  for (int mt = 0; mt < 4; ++mt)
#pragma unroll
    for (int nt = 0; nt < 4; ++nt) { acc[mt][nt][0] = 0.f; acc[mt][nt][1] = 0.f; acc[mt][nt][2] = 0.f; acc[mt][nt][3] = 0.f; }

  const f16* gA = xemb + (int64_t)rb * 128 * E_;
  const f16* gB = wih16 + (int64_t)cb * 128 * E_;

  for (int kb = 0; kb < 8; ++kb) {
    __syncthreads();
#pragma unroll
    for (int i = 0; i < 4; ++i) {
      int idx = i * 256 + tid;
      int row = idx >> 3, u = idx & 7;
      int64_t goff = (int64_t)row * E_ + kb * 64 + u * 8;
      *(half8*)(lA + row * LDK + u * 8) = *(const half8*)(gA + goff);
      *(half8*)(lB + row * LDK + u * 8) = *(const half8*)(gB + goff);
    }
    __syncthreads();
#pragma unroll
    for (int ks = 0; ks < 2; ++ks) {
      half8 af[4], bf[4];
#pragma unroll
      for (int mt = 0; mt < 4; ++mt)
        af[mt] = *(const half8*)(lA + (wm * 64 + mt * 16 + l15) * LDK + ks * 32 + l4 * 8);
#pragma unroll
      for (int nt = 0; nt < 4; ++nt)
        bf[nt] = *(const half8*)(lB + (wn * 64 + nt * 16 + l15) * LDK + ks * 32 + l4 * 8);
#pragma unroll
      for (int mt = 0; mt < 4; ++mt)
#pragma unroll
        for (int nt = 0; nt < 4; ++nt)
          acc[mt][nt] = __builtin_amdgcn_mfma_f32_16x16x32_f16(af[mt], bf[nt], acc[mt][nt], 0, 0, 0);
    }
  }

  // epilogue: Gi2[((t*3072)+col)*32 + n], col = cb*128 + wn*64 + nt*16 + l15
#pragma unroll
  for (int mt = 0; mt < 4; ++mt) {
#pragma unroll
    for (int r = 0; r < 4; ++r) {
      int g = rb * 128 + wm * 64 + mt * 16 + l4 * 4 + r;
      if (g < TS * N_) {
        int tt = g >> 5, n = g & 31;
        f16* gb = gi2 + ((int64_t)tt * 3072 + cb * 128 + wn * 64) * 32 + n;
#pragma unroll
        for (int nt = 0; nt < 4; ++nt)
          gb[(nt * 16 + l15) * 32] = (f16)acc[mt][nt][r];
      }
    }
  }
}

// ---------------- phase B: persistent GRU recurrence, single-XCD placement ----------------
// r0 inner structure (8-wave K-split, LDS partial reduce) + XCD co-residency:
// 1024 candidate wgs; ticket-0 publishes its XCC_ID; wgs on that XCD claim
// slots 0..63, others exit. All h/flag traffic then stays in ONE XCD's L2.
//  - h history: write-once hall[t]. Producer stores AGENT-scope (reach coherence
//    point -> correct even if the group spans XCDs); consumer loads PLAIN 16B
//    (fresh lines, L1-cold; same-XCD -> shared-L2 hit).
//  - flags: agent-scope, per-wg, own 64B line; wave w polls only its 8 producers.
//  - hold carried in-register (f16 roundtrip == store+reload numerics).

__device__ inline unsigned aload32(const void* p) {
  return __hip_atomic_load((const unsigned*)p, __ATOMIC_RELAXED, __HIP_MEMORY_SCOPE_AGENT);
}

__launch_bounds__(512, 1)
__global__ void phaseB(const f16* __restrict__ whh, const f16* __restrict__ gi2,
                       const f16* __restrict__ h0f16, const float* __restrict__ b_ih,
                       const float* __restrict__ b_hh, f16* __restrict__ hall,
                       float* __restrict__ out, unsigned* __restrict__ slots) {
  __shared__ float part[8][32][49];   // padded: conflict-free gate reads
  __shared__ int sh_slot;

  // ---- claim: group 64 wgs on one XCD ----
  unsigned xcd = __builtin_amdgcn_s_getreg(63508) & 0xFu;  // HW_REG_XCC_ID (id=20,off=0,sz=32)
  if (threadIdx.x == 0) {
    unsigned* ticket = slots + 1024;
    unsigned* target = slots + 1028;
    unsigned* slotc  = slots + 1032;
    unsigned tk = __hip_atomic_fetch_add(ticket, 1u, __ATOMIC_RELAXED, __HIP_MEMORY_SCOPE_AGENT);
    if (tk == 0)
      __hip_atomic_store(target, xcd | 0x100u, __ATOMIC_RELAXED, __HIP_MEMORY_SCOPE_AGENT);
    unsigned tgt;
    while ((((tgt = aload32(target))) & 0x100u) == 0) __builtin_amdgcn_s_sleep(1);
    int myslot = -1;
    if ((tgt & 0xFu) == xcd) {
      unsigned s = __hip_atomic_fetch_add(slotc, 1u, __ATOMIC_RELAXED, __HIP_MEMORY_SCOPE_AGENT);
      if (s < NWG_B) myslot = (int)s;
    }
    sh_slot = myslot;
  }
  __syncthreads();
  const int b = sh_slot;
  if (b < 0) return;

  const int tid = threadIdx.x;
  const int w = tid >> 6;
  const int lane = tid & 63;
  const int l15 = lane & 15, l4 = lane >> 4;

  // gate-phase constants: one (n, jl) item per thread
  const int n_g = tid & 31;
  const int jl = tid >> 5;            // 0..15
  const int j = b * 16 + jl;
  const float biasr = b_ih[j] + b_hh[j];
  const float biasz = b_ih[H_ + j] + b_hh[H_ + j];
  const float bihn = b_ih[2 * H_ + j];
  const float bhhn = b_hh[2 * H_ + j];

  // preload w_hh fragments (3 gates x 4 ktiles x 16B = 48 VGPRs)
  half8 wf[3][4];
#pragma unroll
  for (int g = 0; g < 3; ++g) {
    int jt = g * 64 + b;
#pragma unroll
    for (int k = 0; k < 4; ++k)
      wf[g][k] = *(const half8*)(whh + (((int64_t)jt * 32 + (w * 4 + k)) * 64 + lane) * 8);
  }

  unsigned* ownflag = slots + (unsigned)b * 16;
  // wave w consumes producers 8w..8w+7; lane<8 polls one flag each
  const unsigned* pollp = slots + (unsigned)(8 * w + (lane & 7)) * 16;

  // h_old carried in-register
  float hold = (float)h0f16[n_g * H_ + j];

  for (int t = 0; t < TS; ++t) {
    // early independent loads (Gi; written before phaseB, cached)
    const f16* gbase = gi2 + (int64_t)t * 3072 * 32 + n_g;
    float gvr = (float)gbase[(int64_t)j * 32];
    float gvz = (float)gbase[(int64_t)(H_ + j) * 32];
    float gvn = (float)gbase[(int64_t)(2 * H_ + j) * 32];

    // wait for this wave's 8 producers (t=0: flags 0, passes)
    if (lane < 8)
      while (aload32(pollp) < (unsigned)t) __builtin_amdgcn_s_sleep(1);
    asm volatile("" ::: "memory");   // no hoisting of h loads above the poll

    const f16* hp = t ? (hall + (int64_t)(t - 1) * N_ * H_) : h0f16;

    // A fragments: plain 16B loads (write-once lines; same-XCD L2 hit)
    half8 a0[4], a1[4];
#pragma unroll
    for (int k = 0; k < 4; ++k) {
      const f16* base = hp + (w * 4 + k) * 32 + l4 * 8;
      a0[k] = *(const half8*)(base + (int64_t)l15 * H_);
      a1[k] = *(const half8*)(base + (int64_t)(l15 + 16) * H_);
    }

    floatx4 acc[3][2];
#pragma unroll
    for (int g = 0; g < 3; ++g)
#pragma unroll
      for (int m = 0; m < 2; ++m) { acc[g][m][0] = 0.f; acc[g][m][1] = 0.f; acc[g][m][2] = 0.f; acc[g][m][3] = 0.f; }

#pragma unroll
    for (int k = 0; k < 4; ++k) {
#pragma unroll
      for (int g = 0; g < 3; ++g) {
        acc[g][0] = __builtin_amdgcn_mfma_f32_16x16x32_f16(a0[k], wf[g][k], acc[g][0], 0, 0, 0);
        acc[g][1] = __builtin_amdgcn_mfma_f32_16x16x32_f16(a1[k], wf[g][k], acc[g][1], 0, 0, 0);
      }
    }

    // C/D layout: col = lane&15, row = (lane>>4)*4 + reg
#pragma unroll
    for (int g = 0; g < 3; ++g)
#pragma unroll
      for (int m = 0; m < 2; ++m)
#pragma unroll
        for (int r = 0; r < 4; ++r)
          part[w][m * 16 + l4 * 4 + r][g * 16 + l15] = acc[g][m][r];
    __syncthreads();

    float gr = biasr + gvr, gz = biasz + gvz, gin = bihn + gvn, ghn = bhhn;
#pragma unroll
    for (int ww = 0; ww < 8; ++ww) {
      gr += part[ww][n_g][jl];
      gz += part[ww][n_g][16 + jl];
      ghn += part[ww][n_g][32 + jl];
    }
    float rg = 1.f / (1.f + __expf(-gr));
    float zg = 1.f / (1.f + __expf(-gz));
    float nn = tanhf(gin + rg * ghn);
    float hnew = (1.f - zg) * nn + zg * hold;

    // pack (jl, jl^1) pair via cross-lane shuffle (partner tid = tid^32, same wave)
    unsigned short hb = __builtin_bit_cast(unsigned short, (f16)hnew);
    unsigned other = (unsigned)__shfl_xor((int)(unsigned)hb, 32, 64);
    unsigned packed = (unsigned)hb | (other << 16);
    if (!(jl & 1))
      __hip_atomic_store((unsigned*)(hall + ((int64_t)t * N_ + n_g) * H_ + j), packed,
                         __ATOMIC_RELAXED, __HIP_MEMORY_SCOPE_AGENT);

    if (t < TS - 1) {
      __syncthreads();                   // every wave drains vmcnt(0) before barrier
      if (tid == 0) {
        __builtin_amdgcn_s_waitcnt(0);   // belt and suspenders
        __hip_atomic_store(ownflag, (unsigned)(t + 1),
                           __ATOMIC_RELAXED, __HIP_MEMORY_SCOPE_AGENT);
      }
    } else {
      out[32 + n_g * H_ + j] = hnew;
    }

    hold = (float)(f16)hnew;   // identical to store+reload roundtrip
  }
}

// ---------------- phase C: logits GEMM + per-row sum(exp) partials ----------------
// m97 structure: global_load_lds(16B) direct staging, linear LDS [128][64] f16,
// both-sides XOR swizzle, XCD-chunked work mapping (B-tile L2-resident per cb-group).

__device__ inline void gload_lds16(const f16* g, f16* l) {
  __builtin_amdgcn_global_load_lds((const __attribute__((address_space(1))) void*)g,
                                   (__attribute__((address_space(3))) void*)l, 16, 0, 0);
}

__launch_bounds__(256, 2)
__global__ void phaseC(const f16* __restrict__ hall, const f16* __restrict__ emit16,
                       const float* __restrict__ emit_b, float* __restrict__ spart) {
  // bijective XCD-chunk swizzle: 16000 wgs, 2000 per XCD, cb-major work order
  const int wgid = (blockIdx.x & 7) * 2000 + (blockIdx.x >> 3);
  const int cb = wgid >> 6;       // 0..249
  const int rb = wgid & 63;       // 0..63
  const int tid = threadIdx.x;
  const int w = tid >> 6, lane = tid & 63;
  const int wm = w & 1, wn = w >> 1;
  const int l15 = lane & 15, l4 = lane >> 4;

  __shared__ f16 lA[128 * 64];
  __shared__ f16 lB[128 * 64];
  __shared__ float rs[2][128];

  floatx4 acc[4][4];
#pragma unroll
  for (int mt = 0; mt < 4; ++mt)
#pragma unroll
    for (int nt = 0; nt < 4; ++nt) { acc[mt][nt][0] = 0.f; acc[mt][nt][1] = 0.f; acc[mt][nt][2] = 0.f; acc[mt][nt][3] = 0.f; }

  const f16* gA = hall + (int64_t)rb * 128 * H_;
  const f16* gB = emit16 + (int64_t)cb * 128 * H_;

  const int lrow8 = lane >> 3;                 // dest row within 8-row block = row&7
  const int sc = (lane & 7) ^ lrow8;           // pre-swizzled source chunk
  const int rdx = (l15 & 7) << 3;              // read-side XOR (elements)

  for (int kb = 0; kb < 16; ++kb) {
    __syncthreads();
#pragma unroll
    for (int i = 0; i < 4; ++i) {
      const int r0 = w * 32 + i * 8;           // wave-uniform row-block base
      const int64_t goff = (int64_t)(r0 + lrow8) * H_ + kb * 64 + sc * 8;
      gload_lds16(gA + goff, lA + r0 * 64);
      gload_lds16(gB + goff, lB + r0 * 64);
    }
    __syncthreads();                           // drains vmcnt(0): stage visible
#pragma unroll
    for (int ks = 0; ks < 2; ++ks) {
      half8 af[4], bf[4];
      const int col = (ks * 32 + l4 * 8) ^ rdx;
#pragma unroll
      for (int mt = 0; mt < 4; ++mt)
        af[mt] = *(const half8*)(lA + (wm * 64 + mt * 16 + l15) * 64 + col);
#pragma unroll
      for (int nt = 0; nt < 4; ++nt)
        bf[nt] = *(const half8*)(lB + (wn * 64 + nt * 16 + l15) * 64 + col);
#pragma unroll
      for (int mt = 0; mt < 4; ++mt)
#pragma unroll
        for (int nt = 0; nt < 4; ++nt)
          acc[mt][nt] = __builtin_amdgcn_mfma_f32_16x16x32_f16(af[mt], bf[nt], acc[mt][nt], 0, 0, 0);
    }
  }

  // |logits| bounded -> no max-subtraction needed
  float eb[4];
#pragma unroll
  for (int nt = 0; nt < 4; ++nt) eb[nt] = emit_b[cb * 128 + wn * 64 + nt * 16 + l15];

#pragma unroll
  for (int mt = 0; mt < 4; ++mt) {
#pragma unroll
    for (int r = 0; r < 4; ++r) {
      float s = 0.f;
#pragma unroll
      for (int nt = 0; nt < 4; ++nt) s += __expf(acc[mt][nt][r] + eb[nt]);
#pragma unroll
      for (int off = 1; off < 16; off <<= 1) s += __shfl_xor(s, off, 64);
      if (l15 == 0) rs[wn][wm * 64 + mt * 16 + l4 * 4 + r] = s;
    }
  }
  __syncthreads();
  if (tid < 128)
    spart[(int64_t)cb * MROW + rb * 128 + tid] = rs[0][tid] + rs[1][tid];
}

// ---------------- target logits + final reductions ----------------

__global__ void target_dots(const f16* __restrict__ hall, const f16* __restrict__ emit16,
                            const int* __restrict__ words, const float* __restrict__ emit_b,
                            float* __restrict__ tlog) {
  int r = blockIdx.x * 4 + (threadIdx.x >> 6);
  if (r >= TS * N_) return;
  int lane = threadIdx.x & 63;
  int t = r >> 5, n = r & 31;
  int tgt = words[n * T_ + t + 1];
  const f16* ha = hall + (int64_t)r * H_;
  const f16* ebp = emit16 + (int64_t)tgt * H_;
  float s = 0.f;
#pragma unroll
  for (int c = 0; c < 2; ++c) {
    int k = c * 512 + lane * 8;
    half8 a = *(const half8*)(ha + k);
    half8 b = *(const half8*)(ebp + k);
#pragma unroll
    for (int i = 0; i < 8; ++i) s += (float)a[i] * (float)b[i];
  }
#pragma unroll
  for (int off = 1; off < 64; off <<= 1) s += __shfl_xor(s, off, 64);
  if (lane == 0) tlog[r] = s + emit_b[tgt];
}

__global__ void reduce_lse(const float* __restrict__ spart, const float* __restrict__ tlog,
                           float* __restrict__ lval) {
  int r = blockIdx.x * blockDim.x + threadIdx.x;
  if (r >= TS * N_) return;
  float s = 0.f;
  for (int cb = 0; cb < CB_; ++cb) s += spart[(int64_t)cb * MROW + r];
  lval[r] = tlog[r] - logf(s);
}

__global__ void finalize(const float* __restrict__ lval, float* __restrict__ out) {
  __shared__ float ps[8][32];
  int n = threadIdx.x & 31, sl = threadIdx.x >> 5;
  float s = 0.f;
  for (int i = 0; i < 32; ++i) {
    int t = sl * 32 + i;
    if (t < TS) s += lval[t * N_ + n];
  }
  ps[sl][n] = s;
  __syncthreads();
  if (threadIdx.x < 32) {
    float tot = 0.f;
#pragma unroll
    for (int k = 0; k < 8; ++k) tot += ps[k][threadIdx.x];
    out[threadIdx.x] = tot;
  }
}

// ---------------- launch ----------------

extern "C" void kernel_launch(void* const* d_in, const int* in_sizes, int n_in,
                              void* d_out, int out_size, void* d_ws, size_t ws_size,
                              hipStream_t stream) {
  (void)in_sizes; (void)n_in; (void)out_size; (void)ws_size;
  const int*   words   = (const int*)d_in[0];
  const float* h0      = (const float*)d_in[1];
  const float* embed_w = (const float*)d_in[2];
  const float* w_ih    = (const float*)d_in[3];
  const float* w_hh    = (const float*)d_in[4];
  const float* b_ih    = (const float*)d_in[5];
  const float* b_hh    = (const float*)d_in[6];
  const float* emit_w  = (const float*)d_in[7];
  const float* emit_b  = (const float*)d_in[8];
  float* out = (float*)d_out;

  char* ws = (char*)d_ws;
  // ws layout (bytes), total ~100.4 MB. Aliases:
  //  - big region: Gi2 (f16, 50.1 MB, dead after phaseB) then emit16 (65.5 MB, built after phaseB)
  //  - spart (8.19 MB, phaseC) aliases wih16 (dead after gi_gemm)
  f16*      big    = (f16*)(ws + 0);                // 65,536,000
  f16*      gi2    = big;
  f16*      emit16 = big;
  f16*      whh    = (f16*)(ws + 65536000);         //  6,291,456
  f16*      wih16  = (f16*)(ws + 71827456);         //  3,145,728
  float*    spart  = (float*)(ws + 71827456);       //  8,192,000 (alias)
  f16*      xemb   = (f16*)(ws + 74973184);         //  8,388,608 (8192 rows x 512)
  f16*      xh     = (f16*)(ws + 83361792);         //    131,072 (h0 as f16)
  f16*      hall   = (f16*)(ws + 83492864);         // 16,777,216 (write-once h history)
  float*    tlog   = (float*)(ws + 100270080);      //     32,640
  float*    lval   = (float*)(ws + 100302720);      //     32,640
  unsigned* slots  = (unsigned*)(ws + 100335360);   //      8,192 (flags + claim counters)

  hipLaunchKernelGGL(prep_whh, dim3(1536), dim3(256), 0, stream, w_hh, whh);
  hipLaunchKernelGGL(prep_wih16, dim3(768), dim3(256), 0, stream, w_ih, wih16);
  hipLaunchKernelGGL(prep_xemb, dim3(2040), dim3(256), 0, stream, words, embed_w, xemb);
  hipLaunchKernelGGL(prep_init, dim3(128), dim3(256), 0, stream, h0, xh, slots);
  hipLaunchKernelGGL(gi_gemm, dim3(RB_ * GI_CB), dim3(256), 0, stream, xemb, wih16, gi2);
  hipLaunchKernelGGL(phaseB, dim3(CAND_B), dim3(512), 0, stream, whh, gi2, xh, b_ih, b_hh, hall, out, slots);
  hipLaunchKernelGGL(prep_emit16, dim3(4096), dim3(256), 0, stream, emit_w, emit16);
  hipLaunchKernelGGL(phaseC, dim3(RB_ * CB_), dim3(256), 0, stream, hall, emit16, emit_b, spart);
  hipLaunchKernelGGL(target_dots, dim3((TS * N_ + 3) / 4), dim3(256), 0, stream, hall, emit16, words, emit_b, tlog);
  hipLaunchKernelGGL(reduce_lse, dim3((TS * N_ + 255) / 256), dim3(256), 0, stream, spart, tlog, lval);
  hipLaunchKernelGGL(finalize, dim3(1), dim3(256), 0, stream, lval, out);
}

// Round 6
// 2331.268 us; speedup vs baseline: 1.3536x; 1.2304x over previous
//
#include <hip/hip_runtime.h>
#include <cstdint>

// Problem dims
#define V_    32000
#define E_    512
#define H_    1024
#define N_    32
#define T_    256
#define TS    255          // steps = T-1
#define NWG_B 64           // phase B workgroups
#define CB_   250          // phase C col blocks (250*128 = 32000)
#define RB_   64           // seq phase C row blocks (64*128 = 8192)
#define MROW  8192
#define GI_CB 24           // Gi GEMM col blocks (24*128 = 3072)
#define FUSED_WS 150486784ULL

typedef _Float16 f16;
typedef _Float16 half8 __attribute__((ext_vector_type(8)));
typedef float floatx4 __attribute__((ext_vector_type(4)));
typedef unsigned long long u64;

// ---------------- prep kernels ----------------

__global__ void prep_emit16(const float* __restrict__ emit_w, f16* __restrict__ out) {
  const int64_t nchunk = (int64_t)V_ * H_ / 8;
  int64_t i = (int64_t)blockIdx.x * blockDim.x + threadIdx.x;
  for (; i < nchunk; i += (int64_t)gridDim.x * blockDim.x) {
    const float4* src = (const float4*)(emit_w + i * 8);
    float4 a = src[0], b = src[1];
    half8 h;
    h[0] = (f16)a.x; h[1] = (f16)a.y; h[2] = (f16)a.z; h[3] = (f16)a.w;
    h[4] = (f16)b.x; h[5] = (f16)b.y; h[6] = (f16)b.z; h[7] = (f16)b.w;
    *(half8*)(out + i * 8) = h;
  }
}

__global__ void prep_whh(const float* __restrict__ w_hh, f16* __restrict__ whh) {
  int idx = blockIdx.x * blockDim.x + threadIdx.x;   // 192*32*64 = 393216
  if (idx >= 192 * 32 * 64) return;
  int lane = idx & 63;
  int kt   = (idx >> 6) & 31;
  int jt   = (idx >> 6) >> 5;
  int col  = jt * 16 + (lane & 15);
  int k0   = kt * 32 + (lane >> 4) * 8;
  const float* src = w_hh + (int64_t)col * H_ + k0;
  half8 h;
#pragma unroll
  for (int i = 0; i < 8; ++i) h[i] = (f16)src[i];
  *(half8*)(whh + (int64_t)idx * 8) = h;
}

__global__ void prep_wih16(const float* __restrict__ w_ih, f16* __restrict__ out) {
  int idx = blockIdx.x * blockDim.x + threadIdx.x;   // 196608
  if (idx >= 3072 * 512 / 8) return;
  const float4* src = (const float4*)(w_ih + (int64_t)idx * 8);
  float4 a = src[0], b = src[1];
  half8 h;
  h[0] = (f16)a.x; h[1] = (f16)a.y; h[2] = (f16)a.z; h[3] = (f16)a.w;
  h[4] = (f16)b.x; h[5] = (f16)b.y; h[6] = (f16)b.z; h[7] = (f16)b.w;
  *(half8*)(out + (int64_t)idx * 8) = h;
}

__global__ void prep_xemb(const int* __restrict__ words, const float* __restrict__ embed_w,
                          f16* __restrict__ xemb) {
  int idx = blockIdx.x * blockDim.x + threadIdx.x;   // 522240
  if (idx >= TS * N_ * (E_ / 8)) return;
  int u = idx & 63;
  int n = (idx >> 6) & 31;
  int t = idx >> 11;
  int word = words[n * T_ + t];
  const float* src = embed_w + (int64_t)word * E_ + u * 8;
  half8 h;
#pragma unroll
  for (int i = 0; i < 8; ++i) h[i] = (f16)src[i];
  *(half8*)(xemb + (int64_t)(t * N_ + n) * E_ + u * 8) = h;
}

// init Xh (both buffers); zero nslots flag words
__global__ void prep_init(const float* __restrict__ h0, f16* __restrict__ xh,
                          unsigned* __restrict__ slots, int nslots) {
  int idx = blockIdx.x * blockDim.x + threadIdx.x;
  if (idx < N_ * H_) {
    f16 v = (f16)h0[idx];
    xh[idx] = v;
    xh[N_ * H_ + idx] = v;
  }
  if (idx < nslots) slots[idx] = 0;
}

// ---------------- Gi GEMM ----------------

#define LDK 72

__launch_bounds__(256, 2)
__global__ void gi_gemm(const f16* __restrict__ xemb, const f16* __restrict__ wih16,
                        f16* __restrict__ gi2) {
  const int cb = blockIdx.x % GI_CB;
  const int rb = blockIdx.x / GI_CB;
  const int tid = threadIdx.x;
  const int w = tid >> 6, lane = tid & 63;
  const int wm = w & 1, wn = w >> 1;
  const int l15 = lane & 15, l4 = lane >> 4;

  __shared__ f16 lA[128 * LDK];
  __shared__ f16 lB[128 * LDK];

  floatx4 acc[4][4];
#pragma unroll
  for (int mt = 0; mt < 4; ++mt)
#pragma unroll
    for (int nt = 0; nt < 4; ++nt) { acc[mt][nt][0] = 0.f; acc[mt][nt][1] = 0.f; acc[mt][nt][2] = 0.f; acc[mt][nt][3] = 0.f; }

  const f16* gA = xemb + (int64_t)rb * 128 * E_;
  const f16* gB = wih16 + (int64_t)cb * 128 * E_;

  for (int kb = 0; kb < 8; ++kb) {
    __syncthreads();
#pragma unroll
    for (int i = 0; i < 4; ++i) {
      int idx = i * 256 + tid;
      int row = idx >> 3, u = idx & 7;
      int64_t goff = (int64_t)row * E_ + kb * 64 + u * 8;
      *(half8*)(lA + row * LDK + u * 8) = *(const half8*)(gA + goff);
      *(half8*)(lB + row * LDK + u * 8) = *(const half8*)(gB + goff);
    }
    __syncthreads();
#pragma unroll
    for (int ks = 0; ks < 2; ++ks) {
      half8 af[4], bf[4];
#pragma unroll
      for (int mt = 0; mt < 4; ++mt)
        af[mt] = *(const half8*)(lA + (wm * 64 + mt * 16 + l15) * LDK + ks * 32 + l4 * 8);
#pragma unroll
      for (int nt = 0; nt < 4; ++nt)
        bf[nt] = *(const half8*)(lB + (wn * 64 + nt * 16 + l15) * LDK + ks * 32 + l4 * 8);
#pragma unroll
      for (int mt = 0; mt < 4; ++mt)
#pragma unroll
        for (int nt = 0; nt < 4; ++nt)
          acc[mt][nt] = __builtin_amdgcn_mfma_f32_16x16x32_f16(af[mt], bf[nt], acc[mt][nt], 0, 0, 0);
    }
  }

#pragma unroll
  for (int mt = 0; mt < 4; ++mt) {
#pragma unroll
    for (int r = 0; r < 4; ++r) {
      int g = rb * 128 + wm * 64 + mt * 16 + l4 * 4 + r;
      if (g < TS * N_) {
        int tt = g >> 5, n = g & 31;
        f16* gb = gi2 + ((int64_t)tt * 3072 + cb * 128 + wn * 64) * 32 + n;
#pragma unroll
        for (int nt = 0; nt < 4; ++nt)
          gb[(nt * 16 + l15) * 32] = (f16)acc[mt][nt][r];
      }
    }
  }
}

// ---------------- shared atomics helpers ----------------

__device__ inline u64 aload64(const void* p) {
  return __hip_atomic_load((const u64*)p, __ATOMIC_RELAXED, __HIP_MEMORY_SCOPE_AGENT);
}
__device__ inline unsigned aload32(const void* p) {
  return __hip_atomic_load((const unsigned*)p, __ATOMIC_RELAXED, __HIP_MEMORY_SCOPE_AGENT);
}
__device__ inline void astore32(void* p, unsigned v) {
  __hip_atomic_store((unsigned*)p, v, __ATOMIC_RELAXED, __HIP_MEMORY_SCOPE_AGENT);
}

// fence-free barrier (proven r0/r2): 64 slots on distinct cachelines.
__device__ inline void gbar3(unsigned* slots, unsigned tval, int b) {
  __syncthreads();
  if (threadIdx.x == 0) {
    __builtin_amdgcn_s_waitcnt(0);
    astore32(slots + b * 16, tval);
  }
  if (threadIdx.x < 64) {
    unsigned* my = slots + threadIdx.x * 16;
    while (__hip_atomic_load(my, __ATOMIC_RELAXED, __HIP_MEMORY_SCOPE_AGENT) < tval)
      __builtin_amdgcn_s_sleep(1);
  }
  __syncthreads();
}

__device__ inline void gload_lds16(const f16* g, f16* l) {
  __builtin_amdgcn_global_load_lds((const __attribute__((address_space(1))) void*)g,
                                   (__attribute__((address_space(3))) void*)l, 16, 0, 0);
}

// ---------------- sequential phase B (r2 verbatim; fallback path) ----------------

__launch_bounds__(512, 1)
__global__ void phaseB(const f16* __restrict__ whh, const f16* __restrict__ gi2,
                       f16* __restrict__ xh, const float* __restrict__ b_ih,
                       const float* __restrict__ b_hh, f16* __restrict__ hall,
                       float* __restrict__ out, unsigned* __restrict__ slots) {
  const int b = blockIdx.x;
  const int tid = threadIdx.x;
  const int w = tid >> 6;
  const int lane = tid & 63;
  const int l15 = lane & 15, l4 = lane >> 4;

  __shared__ float part[8][32][49];

  const int n_g = tid & 31;
  const int jl = tid >> 5;
  const int j = b * 16 + jl;
  const float biasr = b_ih[j] + b_hh[j];
  const float biasz = b_ih[H_ + j] + b_hh[H_ + j];
  const float bihn = b_ih[2 * H_ + j];
  const float bhhn = b_hh[2 * H_ + j];

  half8 wf[3][4];
#pragma unroll
  for (int g = 0; g < 3; ++g) {
    int jt = g * 64 + b;
#pragma unroll
    for (int k = 0; k < 4; ++k)
      wf[g][k] = *(const half8*)(whh + (((int64_t)jt * 32 + (w * 4 + k)) * 64 + lane) * 8);
  }

  for (int t = 0; t < TS; ++t) {
    const f16* xh_rd = xh + (t & 1) * (N_ * H_);
    f16* xh_wr = xh + ((t + 1) & 1) * (N_ * H_);

    const f16* gbase = gi2 + (int64_t)t * 3072 * 32 + n_g;
    float gvr = (float)gbase[(int64_t)j * 32];
    float gvz = (float)gbase[(int64_t)(H_ + j) * 32];
    float gvn = (float)gbase[(int64_t)(2 * H_ + j) * 32];
    unsigned hraw = aload32(xh_rd + n_g * H_ + (j & ~1));
    unsigned short hbits = (jl & 1) ? (unsigned short)(hraw >> 16) : (unsigned short)(hraw & 0xffffu);
    float hold = (float)__builtin_bit_cast(f16, hbits);

    floatx4 acc[3][2];
#pragma unroll
    for (int g = 0; g < 3; ++g)
#pragma unroll
      for (int m = 0; m < 2; ++m) { acc[g][m][0] = 0.f; acc[g][m][1] = 0.f; acc[g][m][2] = 0.f; acc[g][m][3] = 0.f; }

    half8 a0[4], a1[4];
#pragma unroll
    for (int k = 0; k < 4; ++k) {
      const f16* base = xh_rd + (w * 4 + k) * 32 + l4 * 8;
      union { half8 h; u64 u[2]; } x0, x1;
      const u64* p0 = (const u64*)(base + (int64_t)l15 * H_);
      const u64* p1 = (const u64*)(base + (int64_t)(l15 + 16) * H_);
      x0.u[0] = aload64(p0); x0.u[1] = aload64(p0 + 1);
      x1.u[0] = aload64(p1); x1.u[1] = aload64(p1 + 1);
      a0[k] = x0.h; a1[k] = x1.h;
    }
#pragma unroll
    for (int k = 0; k < 4; ++k) {
#pragma unroll
      for (int g = 0; g < 3; ++g) {
        acc[g][0] = __builtin_amdgcn_mfma_f32_16x16x32_f16(a0[k], wf[g][k], acc[g][0], 0, 0, 0);
        acc[g][1] = __builtin_amdgcn_mfma_f32_16x16x32_f16(a1[k], wf[g][k], acc[g][1], 0, 0, 0);
      }
    }

#pragma unroll
    for (int g = 0; g < 3; ++g)
#pragma unroll
      for (int m = 0; m < 2; ++m)
#pragma unroll
        for (int r = 0; r < 4; ++r)
          part[w][m * 16 + l4 * 4 + r][g * 16 + l15] = acc[g][m][r];
    __syncthreads();

    float gr = biasr + gvr, gz = biasz + gvz, gin = bihn + gvn, ghn = bhhn;
#pragma unroll
    for (int ww = 0; ww < 8; ++ww) {
      gr += part[ww][n_g][jl];
      gz += part[ww][n_g][16 + jl];
      ghn += part[ww][n_g][32 + jl];
    }
    float rg = 1.f / (1.f + __expf(-gr));
    float zg = 1.f / (1.f + __expf(-gz));
    float nn = tanhf(gin + rg * ghn);
    float hnew = (1.f - zg) * nn + zg * hold;

    unsigned short hb = __builtin_bit_cast(unsigned short, (f16)hnew);
    unsigned other = (unsigned)__shfl_xor((int)(unsigned)hb, 32, 64);
    if (!(jl & 1)) {
      unsigned packed = (unsigned)hb | (other << 16);
      astore32((unsigned*)(xh_wr + n_g * H_ + j), packed);
      *(unsigned*)(hall + ((int64_t)t * N_ + n_g) * H_ + j) = packed;
    }
    if (t == TS - 1) out[32 + n_g * H_ + j] = hnew;

    if (t < TS - 1) gbar3(slots, (unsigned)(t + 1), b);
  }
}

// ---------------- sequential phase C (r2 verbatim; fallback path) ----------------

__launch_bounds__(256, 2)
__global__ void phaseC(const f16* __restrict__ hall, const f16* __restrict__ emit16,
                       const float* __restrict__ emit_b, float* __restrict__ spart) {
  const int wgid = (blockIdx.x & 7) * 2000 + (blockIdx.x >> 3);
  const int cb = wgid >> 6;
  const int rb = wgid & 63;
  const int tid = threadIdx.x;
  const int w = tid >> 6, lane = tid & 63;
  const int wm = w & 1, wn = w >> 1;
  const int l15 = lane & 15, l4 = lane >> 4;

  __shared__ f16 lA[128 * 64];
  __shared__ f16 lB[128 * 64];
  __shared__ float rs[2][128];

  floatx4 acc[4][4];
#pragma unroll
  for (int mt = 0; mt < 4; ++mt)
#pragma unroll
    for (int nt = 0; nt < 4; ++nt) { acc[mt][nt][0] = 0.f; acc[mt][nt][1] = 0.f; acc[mt][nt][2] = 0.f; acc[mt][nt][3] = 0.f; }

  const f16* gA = hall + (int64_t)rb * 128 * H_;
  const f16* gB = emit16 + (int64_t)cb * 128 * H_;

  const int lrow8 = lane >> 3;
  const int sc = (lane & 7) ^ lrow8;
  const int rdx = (l15 & 7) << 3;

  for (int kb = 0; kb < 16; ++kb) {
    __syncthreads();
#pragma unroll
    for (int i = 0; i < 4; ++i) {
      const int r0 = w * 32 + i * 8;
      const int64_t goff = (int64_t)(r0 + lrow8) * H_ + kb * 64 + sc * 8;
      gload_lds16(gA + goff, lA + r0 * 64);
      gload_lds16(gB + goff, lB + r0 * 64);
    }
    __syncthreads();
#pragma unroll
    for (int ks = 0; ks < 2; ++ks) {
      half8 af[4], bf[4];
      const int col = (ks * 32 + l4 * 8) ^ rdx;
#pragma unroll
      for (int mt = 0; mt < 4; ++mt)
        af[mt] = *(const half8*)(lA + (wm * 64 + mt * 16 + l15) * 64 + col);
#pragma unroll
      for (int nt = 0; nt < 4; ++nt)
        bf[nt] = *(const half8*)(lB + (wn * 64 + nt * 16 + l15) * 64 + col);
#pragma unroll
      for (int mt = 0; mt < 4; ++mt)
#pragma unroll
        for (int nt = 0; nt < 4; ++nt)
          acc[mt][nt] = __builtin_amdgcn_mfma_f32_16x16x32_f16(af[mt], bf[nt], acc[mt][nt], 0, 0, 0);
    }
  }

  float eb[4];
#pragma unroll
  for (int nt = 0; nt < 4; ++nt) eb[nt] = emit_b[cb * 128 + wn * 64 + nt * 16 + l15];

#pragma unroll
  for (int mt = 0; mt < 4; ++mt) {
#pragma unroll
    for (int r = 0; r < 4; ++r) {
      float s = 0.f;
#pragma unroll
      for (int nt = 0; nt < 4; ++nt) s += __expf(acc[mt][nt][r] + eb[nt]);
#pragma unroll
      for (int off = 1; off < 16; off <<= 1) s += __shfl_xor(s, off, 64);
      if (l15 == 0) rs[wn][wm * 64 + mt * 16 + l4 * 4 + r] = s;
    }
  }
  __syncthreads();
  if (tid < 128)
    spart[(int64_t)cb * MROW + rb * 128 + tid] = rs[0][tid] + rs[1][tid];
}

// ---------------- FUSED phaseB + phaseC (big-ws path) ----------------
// Grid 448 x 512thr, launch_bounds(512,4) + 53KB LDS -> >=2 blocks/CU resident
// (grid <= capacity: no placement deadlock; same co-residency premise phaseB
// already uses). Roles: blocks 0..63 = phaseB (r2 body; hall stores agent-scope,
// + final flag 255). Block 64 = flag aggregator -> replicated tdone lines
// (workers never poll producer flag lines). Blocks 65.. = persistent phaseC
// workers: claim 256x128 tiles (ticket), gate on tdone >= 8*rb+8, compute
// logits sumexp from write-once hall (fresh-line reads: proven r5 pattern).

#define FB_TILES 8000   // 32 rb x 250 cb
#define FB_GRID  448

__launch_bounds__(512, 4)
__global__ void fusedBC(const f16* __restrict__ whh, const f16* __restrict__ gi2,
                        f16* __restrict__ xh, const float* __restrict__ b_ih,
                        const float* __restrict__ b_hh, f16* __restrict__ hall,
                        float* __restrict__ out, unsigned* __restrict__ slots,
                        const f16* __restrict__ emit16, const float* __restrict__ emit_b,
                        float* __restrict__ spart) {
  __shared__ char smem[53248];
  __shared__ unsigned sclaim;
  const int bid = blockIdx.x;
  const int tid = threadIdx.x;

  if (bid < NWG_B) {
    // ================= phaseB role (r2 body) =================
    float (*part)[32][49] = (float (*)[32][49])smem;
    const int b = bid;
    const int w = tid >> 6;
    const int lane = tid & 63;
    const int l15 = lane & 15, l4 = lane >> 4;
    const int n_g = tid & 31;
    const int jl = tid >> 5;
    const int j = b * 16 + jl;
    const float biasr = b_ih[j] + b_hh[j];
    const float biasz = b_ih[H_ + j] + b_hh[H_ + j];
    const float bihn = b_ih[2 * H_ + j];
    const float bhhn = b_hh[2 * H_ + j];

    half8 wf[3][4];
#pragma unroll
    for (int g = 0; g < 3; ++g) {
      int jt = g * 64 + b;
#pragma unroll
      for (int k = 0; k < 4; ++k)
        wf[g][k] = *(const half8*)(whh + (((int64_t)jt * 32 + (w * 4 + k)) * 64 + lane) * 8);
    }

    for (int t = 0; t < TS; ++t) {
      const f16* xh_rd = xh + (t & 1) * (N_ * H_);
      f16* xh_wr = xh + ((t + 1) & 1) * (N_ * H_);

      const f16* gbase = gi2 + (int64_t)t * 3072 * 32 + n_g;
      float gvr = (float)gbase[(int64_t)j * 32];
      float gvz = (float)gbase[(int64_t)(H_ + j) * 32];
      float gvn = (float)gbase[(int64_t)(2 * H_ + j) * 32];
      unsigned hraw = aload32(xh_rd + n_g * H_ + (j & ~1));
      unsigned short hbits = (jl & 1) ? (unsigned short)(hraw >> 16) : (unsigned short)(hraw & 0xffffu);
      float hold = (float)__builtin_bit_cast(f16, hbits);

      floatx4 acc[3][2];
#pragma unroll
      for (int g = 0; g < 3; ++g)
#pragma unroll
        for (int m = 0; m < 2; ++m) { acc[g][m][0] = 0.f; acc[g][m][1] = 0.f; acc[g][m][2] = 0.f; acc[g][m][3] = 0.f; }

      half8 a0[4], a1[4];
#pragma unroll
      for (int k = 0; k < 4; ++k) {
        const f16* base = xh_rd + (w * 4 + k) * 32 + l4 * 8;
        union { half8 h; u64 u[2]; } x0, x1;
        const u64* p0 = (const u64*)(base + (int64_t)l15 * H_);
        const u64* p1 = (const u64*)(base + (int64_t)(l15 + 16) * H_);
        x0.u[0] = aload64(p0); x0.u[1] = aload64(p0 + 1);
        x1.u[0] = aload64(p1); x1.u[1] = aload64(p1 + 1);
        a0[k] = x0.h; a1[k] = x1.h;
      }
#pragma unroll
      for (int k = 0; k < 4; ++k) {
#pragma unroll
        for (int g = 0; g < 3; ++g) {
          acc[g][0] = __builtin_amdgcn_mfma_f32_16x16x32_f16(a0[k], wf[g][k], acc[g][0], 0, 0, 0);
          acc[g][1] = __builtin_amdgcn_mfma_f32_16x16x32_f16(a1[k], wf[g][k], acc[g][1], 0, 0, 0);
        }
      }

#pragma unroll
      for (int g = 0; g < 3; ++g)
#pragma unroll
        for (int m = 0; m < 2; ++m)
#pragma unroll
          for (int r = 0; r < 4; ++r)
            part[w][m * 16 + l4 * 4 + r][g * 16 + l15] = acc[g][m][r];
      __syncthreads();

      float gr = biasr + gvr, gz = biasz + gvz, gin = bihn + gvn, ghn = bhhn;
#pragma unroll
      for (int ww = 0; ww < 8; ++ww) {
        gr += part[ww][n_g][jl];
        gz += part[ww][n_g][16 + jl];
        ghn += part[ww][n_g][32 + jl];
      }
      float rg = 1.f / (1.f + __expf(-gr));
      float zg = 1.f / (1.f + __expf(-gz));
      float nn = tanhf(gin + rg * ghn);
      float hnew = (1.f - zg) * nn + zg * hold;

      unsigned short hb = __builtin_bit_cast(unsigned short, (f16)hnew);
      unsigned other = (unsigned)__shfl_xor((int)(unsigned)hb, 32, 64);
      if (!(jl & 1)) {
        unsigned packed = (unsigned)hb | (other << 16);
        astore32((unsigned*)(xh_wr + n_g * H_ + j), packed);
        // hall read concurrently by workers -> agent-scope store
        astore32((unsigned*)(hall + ((int64_t)t * N_ + n_g) * H_ + j), packed);
      }
      if (t == TS - 1) out[32 + n_g * H_ + j] = hnew;

      if (t < TS - 1) gbar3(slots, (unsigned)(t + 1), b);
    }
    // publish final flag 255 (unlocks rb=31 workers)
    __syncthreads();
    if (tid == 0) {
      __builtin_amdgcn_s_waitcnt(0);
      astore32(slots + b * 16, 255u);
    }
    return;
  }

  if (bid == NWG_B) {
    // ================= aggregator role =================
    if (tid >= 64) return;
    while (true) {
      unsigned v = aload32(slots + tid * 16);
#pragma unroll
      for (int off = 32; off >= 1; off >>= 1) {
        unsigned o = (unsigned)__shfl_xor((int)v, off, 64);
        v = v < o ? v : o;
      }
      if (tid < 16) astore32(slots + 2048 + tid * 16, v);
      if (v >= 255u) return;
      __builtin_amdgcn_s_sleep(8);
    }
  }

  // ================= worker role: phaseC tiles 256x128 =================
  {
    const int w = tid >> 6, lane = tid & 63;
    const int wm = w & 1, wn = w >> 1;
    const int l15 = lane & 15, l4 = lane >> 4;
    const int lrow8 = lane >> 3;
    const int sc = (lane & 7) ^ lrow8;
    const int rdx = (l15 & 7) << 3;
    f16* lA = (f16*)smem;               // 256x64 f16 = 32768 B
    f16* lB = (f16*)(smem + 32768);     // 128x64 f16 = 16384 B
    float* rs = (float*)(smem + 49152); // 4x256 f32 = 4096 B
    unsigned* ticket = slots + 1024;
    const unsigned* tline = slots + 2048 + (bid & 15) * 16;

    while (true) {
      if (tid == 0)
        sclaim = __hip_atomic_fetch_add(ticket, 1u, __ATOMIC_RELAXED, __HIP_MEMORY_SCOPE_AGENT);
      __syncthreads();
      const unsigned c = sclaim;
      __syncthreads();
      if (c >= FB_TILES) return;
      const int rb = (int)(c / 250u);
      const int cb = (int)(c % 250u);
      const unsigned thr = (rb == 31) ? 255u : (unsigned)(8 * rb + 8);
      if (tid == 0)
        while (aload32(tline) < thr) __builtin_amdgcn_s_sleep(32);
      __syncthreads();
      asm volatile("" ::: "memory");

      const f16* gA = hall + (int64_t)rb * 256 * H_;
      const f16* gB = emit16 + (int64_t)cb * 128 * H_;

      floatx4 acc[8][2];
#pragma unroll
      for (int mt = 0; mt < 8; ++mt)
#pragma unroll
        for (int nt = 0; nt < 2; ++nt) { acc[mt][nt][0] = 0.f; acc[mt][nt][1] = 0.f; acc[mt][nt][2] = 0.f; acc[mt][nt][3] = 0.f; }

      for (int kb = 0; kb < 16; ++kb) {
        __syncthreads();
        // A: wave w stages rows [w*32, w*32+32)
#pragma unroll
        for (int i = 0; i < 4; ++i) {
          const int r0 = w * 32 + i * 8;
          gload_lds16(gA + (int64_t)(r0 + lrow8) * H_ + kb * 64 + sc * 8, lA + r0 * 64);
        }
        // B: wave w stages rows [w*16, w*16+16)
#pragma unroll
        for (int i = 0; i < 2; ++i) {
          const int r0 = w * 16 + i * 8;
          gload_lds16(gB + (int64_t)(r0 + lrow8) * H_ + kb * 64 + sc * 8, lB + r0 * 64);
        }
        __syncthreads();
#pragma unroll
        for (int ks = 0; ks < 2; ++ks) {
          half8 af[8], bf[2];
          const int col = (ks * 32 + l4 * 8) ^ rdx;
#pragma unroll
          for (int mt = 0; mt < 8; ++mt)
            af[mt] = *(const half8*)(lA + (wm * 128 + mt * 16 + l15) * 64 + col);
#pragma unroll
          for (int nt = 0; nt < 2; ++nt)
            bf[nt] = *(const half8*)(lB + (wn * 32 + nt * 16 + l15) * 64 + col);
#pragma unroll
          for (int mt = 0; mt < 8; ++mt)
#pragma unroll
            for (int nt = 0; nt < 2; ++nt)
              acc[mt][nt] = __builtin_amdgcn_mfma_f32_16x16x32_f16(af[mt], bf[nt], acc[mt][nt], 0, 0, 0);
        }
      }

      float eb[2];
#pragma unroll
      for (int nt = 0; nt < 2; ++nt) eb[nt] = emit_b[cb * 128 + wn * 32 + nt * 16 + l15];

#pragma unroll
      for (int mt = 0; mt < 8; ++mt) {
#pragma unroll
        for (int r = 0; r < 4; ++r) {
          float s = __expf(acc[mt][0][r] + eb[0]) + __expf(acc[mt][1][r] + eb[1]);
#pragma unroll
          for (int off = 1; off < 16; off <<= 1) s += __shfl_xor(s, off, 64);
          if (l15 == 0) rs[wn * 256 + wm * 128 + mt * 16 + l4 * 4 + r] = s;
        }
      }
      __syncthreads();
      if (tid < 256)
        spart[(int64_t)cb * MROW + rb * 256 + tid] =
            rs[tid] + rs[256 + tid] + rs[512 + tid] + rs[768 + tid];
    }
  }
}

// ---------------- target logits + final reductions ----------------

__global__ void target_dots(const f16* __restrict__ hall, const f16* __restrict__ emit16,
                            const int* __restrict__ words, const float* __restrict__ emit_b,
                            float* __restrict__ tlog) {
  int r = blockIdx.x * 4 + (threadIdx.x >> 6);
  if (r >= TS * N_) return;
  int lane = threadIdx.x & 63;
  int t = r >> 5, n = r & 31;
  int tgt = words[n * T_ + t + 1];
  const f16* ha = hall + (int64_t)r * H_;
  const f16* ebp = emit16 + (int64_t)tgt * H_;
  float s = 0.f;
#pragma unroll
  for (int c = 0; c < 2; ++c) {
    int k = c * 512 + lane * 8;
    half8 a = *(const half8*)(ha + k);
    half8 b = *(const half8*)(ebp + k);
#pragma unroll
    for (int i = 0; i < 8; ++i) s += (float)a[i] * (float)b[i];
  }
#pragma unroll
  for (int off = 1; off < 64; off <<= 1) s += __shfl_xor(s, off, 64);
  if (lane == 0) tlog[r] = s + emit_b[tgt];
}

__global__ void reduce_lse(const float* __restrict__ spart, const float* __restrict__ tlog,
                           float* __restrict__ lval) {
  int r = blockIdx.x * blockDim.x + threadIdx.x;
  if (r >= TS * N_) return;
  float s = 0.f;
  for (int cb = 0; cb < CB_; ++cb) s += spart[(int64_t)cb * MROW + r];
  lval[r] = tlog[r] - logf(s);
}

__global__ void finalize(const float* __restrict__ lval, float* __restrict__ out) {
  __shared__ float ps[8][32];
  int n = threadIdx.x & 31, sl = threadIdx.x >> 5;
  float s = 0.f;
  for (int i = 0; i < 32; ++i) {
    int t = sl * 32 + i;
    if (t < TS) s += lval[t * N_ + n];
  }
  ps[sl][n] = s;
  __syncthreads();
  if (threadIdx.x < 32) {
    float tot = 0.f;
#pragma unroll
    for (int k = 0; k < 8; ++k) tot += ps[k][threadIdx.x];
    out[threadIdx.x] = tot;
  }
}

// ---------------- launch ----------------

extern "C" void kernel_launch(void* const* d_in, const int* in_sizes, int n_in,
                              void* d_out, int out_size, void* d_ws, size_t ws_size,
                              hipStream_t stream) {
  (void)in_sizes; (void)n_in; (void)out_size;
  const int*   words   = (const int*)d_in[0];
  const float* h0      = (const float*)d_in[1];
  const float* embed_w = (const float*)d_in[2];
  const float* w_ih    = (const float*)d_in[3];
  const float* w_hh    = (const float*)d_in[4];
  const float* b_ih    = (const float*)d_in[5];
  const float* b_hh    = (const float*)d_in[6];
  const float* emit_w  = (const float*)d_in[7];
  const float* emit_b  = (const float*)d_in[8];
  float* out = (float*)d_out;

  char* ws = (char*)d_ws;

  if (ws_size >= FUSED_WS) {
    // ---- fused layout (~150.5 MB): gi2 + emit16 coexist ----
    f16*      emit16 = (f16*)(ws + 0);                //  65,536,000
    f16*      gi2    = (f16*)(ws + 65536000);         //  50,135,040
    f16*      whh    = (f16*)(ws + 115671040);        //   6,291,456
    f16*      xemb   = (f16*)(ws + 121962496);        //   8,388,608 (dead after gi_gemm)
    float*    spart  = (float*)(ws + 121962496);      //   8,192,000 (alias xemb)
    f16*      wih16  = (f16*)(ws + 130351104);        //   3,145,728
    f16*      xh     = (f16*)(ws + 133496832);        //     131,072
    f16*      hall   = (f16*)(ws + 133627904);        //  16,777,216
    float*    tlog   = (float*)(ws + 150405120);      //      32,640
    float*    lval   = (float*)(ws + 150437760);      //      32,640
    unsigned* slots  = (unsigned*)(ws + 150470400);   //      16,384

    hipLaunchKernelGGL(prep_whh, dim3(1536), dim3(256), 0, stream, w_hh, whh);
    hipLaunchKernelGGL(prep_wih16, dim3(768), dim3(256), 0, stream, w_ih, wih16);
    hipLaunchKernelGGL(prep_xemb, dim3(2040), dim3(256), 0, stream, words, embed_w, xemb);
    hipLaunchKernelGGL(prep_init, dim3(128), dim3(256), 0, stream, h0, xh, slots, 4096);
    hipLaunchKernelGGL(prep_emit16, dim3(4096), dim3(256), 0, stream, emit_w, emit16);
    hipLaunchKernelGGL(gi_gemm, dim3(RB_ * GI_CB), dim3(256), 0, stream, xemb, wih16, gi2);
    hipLaunchKernelGGL(fusedBC, dim3(FB_GRID), dim3(512), 0, stream,
                       whh, gi2, xh, b_ih, b_hh, hall, out, slots, emit16, emit_b, spart);
    hipLaunchKernelGGL(target_dots, dim3((TS * N_ + 3) / 4), dim3(256), 0, stream, hall, emit16, words, emit_b, tlog);
    hipLaunchKernelGGL(reduce_lse, dim3((TS * N_ + 255) / 256), dim3(256), 0, stream, spart, tlog, lval);
    hipLaunchKernelGGL(finalize, dim3(1), dim3(256), 0, stream, lval, out);
  } else {
    // ---- sequential fallback (r2 layout, ~100.4 MB) ----
    f16*      big    = (f16*)(ws + 0);                // 65,536,000
    f16*      gi2    = big;
    f16*      emit16 = big;
    f16*      whh    = (f16*)(ws + 65536000);         //  6,291,456
    f16*      wih16  = (f16*)(ws + 71827456);         //  3,145,728
    float*    spart  = (float*)(ws + 71827456);       //  8,192,000 (alias)
    f16*      xemb   = (f16*)(ws + 74973184);         //  8,388,608
    f16*      xh     = (f16*)(ws + 83361792);         //    131,072
    f16*      hall   = (f16*)(ws + 83492864);         // 16,777,216
    float*    tlog   = (float*)(ws + 100270080);      //     32,640
    float*    lval   = (float*)(ws + 100302720);      //     32,640
    unsigned* slots  = (unsigned*)(ws + 100335360);   //      4,096

    hipLaunchKernelGGL(prep_whh, dim3(1536), dim3(256), 0, stream, w_hh, whh);
    hipLaunchKernelGGL(prep_wih16, dim3(768), dim3(256), 0, stream, w_ih, wih16);
    hipLaunchKernelGGL(prep_xemb, dim3(2040), dim3(256), 0, stream, words, embed_w, xemb);
    hipLaunchKernelGGL(prep_init, dim3(128), dim3(256), 0, stream, h0, xh, slots, 1024);
    hipLaunchKernelGGL(gi_gemm, dim3(RB_ * GI_CB), dim3(256), 0, stream, xemb, wih16, gi2);
    hipLaunchKernelGGL(phaseB, dim3(NWG_B), dim3(512), 0, stream, whh, gi2, xh, b_ih, b_hh, hall, out, slots);
    hipLaunchKernelGGL(prep_emit16, dim3(4096), dim3(256), 0, stream, emit_w, emit16);
    hipLaunchKernelGGL(phaseC, dim3(RB_ * CB_), dim3(256), 0, stream, hall, emit16, emit_b, spart);
    hipLaunchKernelGGL(target_dots, dim3((TS * N_ + 3) / 4), dim3(256), 0, stream, hall, emit16, words, emit_b, tlog);
    hipLaunchKernelGGL(reduce_lse, dim3((TS * N_ + 255) / 256), dim3(256), 0, stream, spart, tlog, lval);
    hipLaunchKernelGGL(finalize, dim3(1), dim3(256), 0, stream, lval, out);
  }
}